// Round 8
// baseline (727.379 us; speedup 1.0000x reference)
//
#include <hip/hip_runtime.h>
#include <math.h>

#define N_ROWS 32768
#define KCB    8192
#define DIM    512
#define BETA   0.25f
#define MARGIN 2e-3f
#define FLAG_SLACK 1e-4f
#define CAND_CAP 256

typedef __attribute__((ext_vector_type(4))) float  f32x4;
typedef __attribute__((ext_vector_type(4))) int    i32x4;
typedef __attribute__((ext_vector_type(8))) int    i32x8;

__device__ __forceinline__ unsigned short f2h(float x) {
    _Float16 h = (_Float16)x;
    return *(unsigned short*)&h;
}
__device__ __forceinline__ float h2f(unsigned short u) {
    _Float16 h = *(_Float16*)&u;
    return (float)h;
}

// ---------------------------------------------------------------------------
// Kernel 1 (fused pre-pass): sq (numpy-exact pairwise tree) + fp8 convert.
// (R7's LDS-staged sq retained — neutral but harmless.)
// ---------------------------------------------------------------------------
#define SQ_BLOCKS ((N_ROWS + KCB) / 8)
__global__ __launch_bounds__(256) void pre_kernel(
        const float* __restrict__ lat, const float* __restrict__ emb,
        float* __restrict__ row_sq, float* __restrict__ emb_sq,
        unsigned char* __restrict__ latq, unsigned char* __restrict__ embq,
        int* __restrict__ counter) {
    if (blockIdx.x < SQ_BLOCKS) {
#pragma clang fp contract(off)
        __shared__ float xs[8 * 516];
        if (blockIdx.x == 0 && threadIdx.x == 0) *counter = 0;
        for (int f = threadIdx.x; f < 1024; f += 256) {
            int rl   = f >> 7;
            int col4 = f & 127;
            int grow = blockIdx.x * 8 + rl;
            const float* src = (grow < N_ROWS)
                ? (lat + (size_t)grow * DIM)
                : (emb + (size_t)(grow - N_ROWS) * DIM);
            float4 v = ((const float4*)src)[col4];
            *(float4*)&xs[rl * 516 + col4 * 4] = v;
        }
        __syncthreads();
        const int w    = threadIdx.x >> 6;
        const int lane = threadIdx.x & 63;
        const int half = lane >> 5;
        const int L    = lane & 31;
        const int b    = L >> 3, j = L & 7;
        const int rl   = w * 2 + half;
        const int row  = blockIdx.x * 8 + rl;
        const float* q = xs + rl * 516 + 128 * b + j;
        float a0 = q[0];
        float r  = a0 * a0;
        for (int i = 1; i < 16; ++i) {
            float a = q[8 * i];
            float s = a * a;
            r = r + s;
        }
        r = r + __shfl_xor(r, 1);
        r = r + __shfl_xor(r, 2);
        r = r + __shfl_xor(r, 4);
        r = r + __shfl_xor(r, 8);
        r = r + __shfl_xor(r, 16);
        if (L == 0) {
            if (row < N_ROWS) row_sq[row] = r;
            else              emb_sq[row - N_ROWS] = r;
        }
    } else {
        const size_t NL8 = (size_t)N_ROWS * DIM / 8;
        const size_t NE8 = (size_t)KCB * DIM / 8;
        size_t g = (size_t)(blockIdx.x - SQ_BLOCKS) * 256 + threadIdx.x;
        const float* src; unsigned char* dst; size_t i; float sc;
        if (g < NL8)            { src = lat; dst = latq; i = g;       sc = 1.0f; }
        else if (g < NL8 + NE8) { src = emb; dst = embq; i = g - NL8; sc = 8192.0f; }
        else return;
        float4 v0 = ((const float4*)src)[2 * i];
        float4 v1 = ((const float4*)src)[2 * i + 1];
        int lo = __builtin_amdgcn_cvt_pk_fp8_f32(v0.x * sc, v0.y * sc, 0,  false);
        lo     = __builtin_amdgcn_cvt_pk_fp8_f32(v0.z * sc, v0.w * sc, lo, true);
        int hi = __builtin_amdgcn_cvt_pk_fp8_f32(v1.x * sc, v1.y * sc, 0,  false);
        hi     = __builtin_amdgcn_cvt_pk_fp8_f32(v1.z * sc, v1.w * sc, hi, true);
        ((int2*)dst)[i] = make_int2(lo, hi);
    }
}

// ---------------------------------------------------------------------------
// Kernel 2: MX-scaled fp8 MFMA GEMM (transposed: D[code][latrow]).
// R8: B-operand (lat rows) moves from LDS staging to DIRECT global->register
// loads. Rationale: gemm is latency-bound (MfmaUtil 25%, no pipe >40%,
// occupancy 1.75 blocks/CU, LDS-capped at 64 KB). B has only 2-way reuse
// per block, and the B fragment is exactly two contiguous 16-B reads at
// k0 + q*32 (+16) of the lat row — no swizzle needed from global. Dropping
// the Br buffers halves LDS (64->32 KB/block) and staging loads (8->4 per
// wave, vmcnt(4)), lifting occupancy to 3-4 blocks/CU. Extra latq reads
// are served by the supertile-resident L2 slice. A path (LDS dbuf +
// both-sides XOR swizzle), acc layout, epilogue, XCD supertile map are
// UNCHANGED from the verified R1 kernel. launch_bounds(256,3): relaxed
// VGPR ceiling (~170) -- no tight cap (R3 spill lesson).
// ---------------------------------------------------------------------------
__device__ __forceinline__ void load16_to_lds(const void* g, void* l) {
    __builtin_amdgcn_global_load_lds(
        (const __attribute__((address_space(1))) unsigned int*)g,
        (__attribute__((address_space(3))) unsigned int*)l, 16, 0, 0);
}

__global__ __launch_bounds__(256, 3) void gemm_kernel(
        const unsigned char* __restrict__ latq,
        const unsigned char* __restrict__ embq,
        const float* __restrict__ emb_sq,
        unsigned int* __restrict__ packed) {
    __shared__ unsigned char Ac[2][128 * 128];   // codes, 2 x 16 KB, swizzled

    const int tid   = threadIdx.x;
    const int w     = tid >> 6;
    const int lane  = tid & 63;
    const int q     = lane >> 4;
    const int m16   = lane & 15;

    // XCD-chunked supertile swizzle (bijective: 16384 = 8 XCD * 2048).
    const int b   = blockIdx.x;
    const int l   = (b & 7) * 2048 + (b >> 3);
    const int st  = l >> 9;          // 0..31
    const int r2  = l & 511;
    const int rg  = st & 7;          // 8 row groups of 32 tiles
    const int cg  = st >> 3;         // 4 code groups of 16 tiles
    const int row0  = (rg * 32 + (r2 & 31)) * 128;
    const int code0 = (cg * 16 + (r2 >> 5)) * 128;

    const int wc    = 64 * (w >> 1);
    const int rbase = 64 * (w & 1);

    // A staging: 16 chunks of 1 KB, 4 per wave. Chunk h covers 8 code rows
    // x 128 B. Lane l writes LDS linear h*1024 + l*16 (row h*8+(l>>3), slot
    // l&7). Source slot pre-swizzled: (l&7)^(l>>3), so
    // LDS[row][s] = global[row][s ^ (row&7)] (16B slot units).
    int soff[4];
#pragma unroll
    for (int i = 0; i < 4; ++i) {
        int h = w * 4 + i;
        soff[i] = (code0 + h * 8 + (lane >> 3)) * DIM
                + (((lane & 7) ^ (lane >> 3)) << 4);
    }

#define STAGE_A(bsel, k0)                                                   \
    do {                                                                    \
        _Pragma("unroll")                                                   \
        for (int i = 0; i < 4; ++i) {                                       \
            load16_to_lds(embq + soff[i] + (k0),                            \
                          &Ac[bsel][(w * 4 + i) * 1024]);                   \
        }                                                                   \
    } while (0)

    // B base: lane (m16,q) reads lat row (row0+rbase+16c+m16), bytes
    // k0 + q*32 .. +31 (two dwordx4). No swizzle: direct global.
    const unsigned char* bbase =
        latq + (size_t)(row0 + rbase + m16) * DIM + q * 32;

    f32x4 acc[4][4];
#pragma unroll
    for (int r = 0; r < 4; ++r)
#pragma unroll
        for (int c = 0; c < 4; ++c) acc[r][c] = (f32x4){0.f, 0.f, 0.f, 0.f};

    const int sw = (m16 & 7) << 4;   // per-lane row-XOR (row&7 == m16&7)

    STAGE_A(0, 0);                   // prologue: A tile 0 in flight

#pragma unroll
    for (int t = 0; t < 4; ++t) {
        const int bsel = t & 1;
        if (t < 3) STAGE_A((t + 1) & 1, (t + 1) * 128);  // prefetch A t+1
        __builtin_amdgcn_sched_barrier(0);
        if (t < 3) { asm volatile("s_waitcnt vmcnt(4)" ::: "memory"); }
        else       { asm volatile("s_waitcnt vmcnt(0)" ::: "memory"); }
        __builtin_amdgcn_s_barrier();        // A tile t visible to all waves
        __builtin_amdgcn_sched_barrier(0);

        // B fragments: direct global loads (L2-resident supertile slice).
        i32x8 bv[4];
#pragma unroll
        for (int c = 0; c < 4; ++c) {
            const unsigned char* g = bbase + (size_t)(16 * c) * DIM + t * 128;
            i32x4 lo = *(const i32x4*)g;
            i32x4 hi = *(const i32x4*)(g + 16);
            bv[c] = (i32x8){lo[0], lo[1], lo[2], lo[3],
                            hi[0], hi[1], hi[2], hi[3]};
        }
        // A side streams: per r, 2 ds_reads -> af -> 4 MFMAs.
#pragma unroll
        for (int r = 0; r < 4; ++r) {
            int roff = (wc + 16 * r + m16) * 128;
            i32x4 lo = *(const i32x4*)&Ac[bsel][roff + ((q * 32) ^ sw)];
            i32x4 hi = *(const i32x4*)&Ac[bsel][roff + ((q * 32 + 16) ^ sw)];
            i32x8 af = (i32x8){lo[0], lo[1], lo[2], lo[3],
                               hi[0], hi[1], hi[2], hi[3]};
#pragma unroll
            for (int c = 0; c < 4; ++c)
                acc[r][c] = __builtin_amdgcn_mfma_scale_f32_16x16x128_f8f6f4(
                    af, bv[c], acc[r][c],
                    0, 0,                 // cbsz=fp8(e4m3), blgp=fp8(e4m3)
                    0, 0x7F7F7F7F,        // scale A: e8m0 127 -> 1.0
                    0, 0x7F7F7F7F);       // scale B: e8m0 127 -> 1.0
        }
        __builtin_amdgcn_sched_barrier(0);
        __builtin_amdgcn_s_barrier();        // all waves done reading Ac buf
        __builtin_amdgcn_sched_barrier(0);
    }
#undef STAGE_A

    float sev[4][4];
#pragma unroll
    for (int r = 0; r < 4; ++r)
#pragma unroll
        for (int reg = 0; reg < 4; ++reg)
            sev[r][reg] = emb_sq[code0 + wc + 16 * r + 4 * q + reg];

    // epilogue (sx-free): s_rel = se - 2^-12*dotq ; group min + nibble bitmap
    const float inv = 1.0f / 4096.0f;
#pragma unroll
    for (int c = 0; c < 4; ++c) {
        unsigned pk[4];
#pragma unroll
        for (int r = 0; r < 4; ++r) {
            float s0 = sev[r][0] - acc[r][c][0] * inv;
            float s1 = sev[r][1] - acc[r][c][1] * inv;
            float s2 = sev[r][2] - acc[r][c][2] * inv;
            float s3 = sev[r][3] - acc[r][c][3] * inv;
            float mn = fminf(fminf(s0, s1), fminf(s2, s3));
            mn = fminf(mn, __shfl_xor(mn, 16));
            mn = fminf(mn, __shfl_xor(mn, 32));
            float t = mn + MARGIN;
            unsigned nib = (s0 <= t ? 1u : 0u) | (s1 <= t ? 2u : 0u)
                         | (s2 <= t ? 4u : 0u) | (s3 <= t ? 8u : 0u);
            nib <<= (4 * q);
            nib |= (unsigned)__shfl_xor((int)nib, 16);
            nib |= (unsigned)__shfl_xor((int)nib, 32);
            pk[r] = ((unsigned)f2h(mn)) | (nib << 16);
        }
        if (lane < 16) {
            int grow = row0 + rbase + 16 * c + m16;
            int base = (code0 + wc) >> 4;
            *(uint4*)&packed[(size_t)grow * 512 + base] =
                make_uint4(pk[0], pk[1], pk[2], pk[3]);
        }
    }
}

// ---------------------------------------------------------------------------
// Kernel 3 (fused): global min of fp16 group mins -> flagged groups ->
// candidate codes -> exact fp32 rescore (R1's bit-identical chain) -> outputs.
// ---------------------------------------------------------------------------
__global__ __launch_bounds__(256) void argmin_out_kernel(
        const float* __restrict__ lat, const float* __restrict__ emb,
        const float* __restrict__ row_sq, const float* __restrict__ emb_sq,
        const unsigned int* __restrict__ packed,
        const int* __restrict__ gold,
        float* __restrict__ out, int* __restrict__ counter) {
    __shared__ float xs[4][DIM];
    __shared__ int   s_cnt[4];
    __shared__ int   s_list[4][CAND_CAP];
    const int w    = threadIdx.x >> 6;
    const int lane = threadIdx.x & 63;
    const int row  = blockIdx.x * 4 + w;

    {
        const float4* xp = (const float4*)(lat + (size_t)row * DIM);
        ((float4*)xs[w])[lane]      = xp[lane];
        ((float4*)xs[w])[lane + 64] = xp[lane + 64];
    }
    const float sx = row_sq[row];
    const float* xw = xs[w];

    unsigned u[8];
    {
        const uint4* tb = (const uint4*)(packed + (size_t)row * 512 + lane * 8);
        uint4 v0 = tb[0], v1 = tb[1];
        u[0] = v0.x; u[1] = v0.y; u[2] = v0.z; u[3] = v0.w;
        u[4] = v1.x; u[5] = v1.y; u[6] = v1.z; u[7] = v1.w;
    }
    float tm[8];
#pragma unroll
    for (int j = 0; j < 8; ++j) tm[j] = h2f((unsigned short)(u[j] & 0xFFFFu));
    float m = tm[0];
#pragma unroll
    for (int j = 1; j < 8; ++j) m = fminf(m, tm[j]);
#pragma unroll
    for (int off = 1; off < 64; off <<= 1)
        m = fminf(m, __shfl_xor(m, off));
    const float thresh = m + (MARGIN + FLAG_SLACK);

    if (lane == 0) s_cnt[w] = 0;
    __syncthreads();
#pragma unroll
    for (int j = 0; j < 8; ++j) {
        if (tm[j] <= thresh) {
            int g = lane * 8 + j;
            unsigned bm = u[j] >> 16;
            while (bm) {
                int b = __ffs(bm) - 1;
                bm &= bm - 1;
                int pos = atomicAdd(&s_cnt[w], 1);
                if (pos < CAND_CAP) s_list[w][pos] = g * 16 + b;
            }
        }
    }
    __syncthreads();
    const int cnt = min(s_cnt[w], CAND_CAP);

    float bd = INFINITY;
    int   bi = 0x7fffffff;
    for (int base = 0; base < cnt; base += 64) {
        int ci = base + lane;
        float dvl = INFINITY;
        int   cl  = 0x7fffffff;
        if (ci < cnt) {
            int code = s_list[w][ci];
            const float* ep = emb + (size_t)code * DIM;
            float acc = 0.0f;
            for (int d = 0; d < DIM; d += 8) {
                float ev[8], xv[8];
#pragma unroll
                for (int t = 0; t < 8; ++t) { ev[t] = ep[d + t]; xv[t] = xw[d + t]; }
#pragma unroll
                for (int t = 0; t < 8; ++t) acc = fmaf(xv[t], ev[t], acc);
            }
            float a = sx + emb_sq[code];
            dvl = a - 2.0f * acc;
            cl  = code;
        }
        if (dvl < bd || (dvl == bd && cl < bi)) { bd = dvl; bi = cl; }
    }
#pragma unroll
    for (int off = 1; off < 64; off <<= 1) {
        float od = __shfl_xor(bd, off);
        int   oi = __shfl_xor(bi, off);
        if (od < bd || (od == bd && oi < bi)) { bd = od; bi = oi; }
    }
    const int idx = bi;

    const float4* e4 = (const float4*)(emb + (size_t)idx * DIM);
    float4*       q4 = (float4*)(out + (size_t)row * DIM);
    q4[lane]      = e4[lane];
    q4[lane + 64] = e4[lane + 64];

    float r = 0.0f;
    if (lane < 32) {
        const int b = lane >> 3, j = lane & 7;
        const float* ep = emb + (size_t)idx * DIM + b * 128 + j;
        const float* xp = xw + b * 128 + j;
        for (int i = 0; i < 16; ++i) {
            float dq = ep[8 * i] - xp[8 * i];
            float s  = dq * dq;
            r = (i == 0) ? s : (r + s);
        }
    }
    for (int mm = 1; mm <= 16; mm <<= 1) {
        float o = __shfl_xor(r, mm);
        r = r + o;
    }
    if (lane == 0) {
        float mean = r * (1.0f / 512.0f);
        float v    = mean + 0.25f * mean;
        out[(size_t)N_ROWS * DIM + row]          = v;
        out[(size_t)N_ROWS * DIM + N_ROWS + row] = (float)idx;
        if (gold[row] == idx) atomicAdd(counter, 1);
    }
}

__global__ void tail_kernel(const int* __restrict__ counter,
                            float* __restrict__ out) {
    if (threadIdx.x == 0 && blockIdx.x == 0) {
        const size_t off = (size_t)N_ROWS * DIM + 2 * (size_t)N_ROWS;
        out[off]     = (float)(*counter);
        out[off + 1] = (float)N_ROWS;
    }
}

// ---------------------------------------------------------------------------
// Fallback path (tiny ws): R1 fp32 dist + separate sq/out kernels.
// ---------------------------------------------------------------------------
__global__ __launch_bounds__(256) void sq_kernel(
        const float* __restrict__ lat, const float* __restrict__ emb,
        float* __restrict__ row_sq, float* __restrict__ emb_sq) {
#pragma clang fp contract(off)
    const int w    = threadIdx.x >> 6;
    const int lane = threadIdx.x & 63;
    const int half = lane >> 5;
    const int L    = lane & 31;
    const int b    = L >> 3, j = L & 7;
    const int row  = blockIdx.x * 8 + w * 2 + half;
    if (row >= N_ROWS + KCB) return;
    const float* p = (row < N_ROWS) ? (lat + (size_t)row * DIM)
                                    : (emb + (size_t)(row - N_ROWS) * DIM);
    const float* q = p + 128 * b + j;
    float a0 = q[0];
    float r  = a0 * a0;
    for (int i = 1; i < 16; ++i) {
        float a = q[8 * i];
        float s = a * a;
        r = r + s;
    }
    r = r + __shfl_xor(r, 1);
    r = r + __shfl_xor(r, 2);
    r = r + __shfl_xor(r, 4);
    r = r + __shfl_xor(r, 8);
    r = r + __shfl_xor(r, 16);
    if (L == 0) {
        if (row < N_ROWS) row_sq[row] = r;
        else              emb_sq[row - N_ROWS] = r;
    }
}

#define BM 64
#define BK 128
#define BD 32
__global__ __launch_bounds__(256) void dist_kernel(
        const float* __restrict__ lat, const float* __restrict__ emb,
        const float* __restrict__ row_sq, const float* __restrict__ emb_sq,
        int* __restrict__ enc) {
    __shared__ float xsh[BD][BM];
    __shared__ float esh[BD][BK];
    const int tid  = threadIdx.x;
    const int trow = tid >> 4;
    const int tcol = tid & 15;
    const int row0 = blockIdx.x * BM;
    float bd[4]; int bi[4];
    for (int i = 0; i < 4; ++i) { bd[i] = INFINITY; bi[i] = 0; }
    float sx[4];
    for (int i = 0; i < 4; ++i) sx[i] = row_sq[row0 + 4 * trow + i];
    for (int kt = 0; kt < KCB; kt += BK) {
        float acc[4][8] = {};
        for (int d0 = 0; d0 < DIM; d0 += BD) {
            for (int f = tid; f < BM * BD / 4; f += 256) {
                int r = f >> 3, c4 = f & 7;
                float4 v = *(const float4*)(lat + (size_t)(row0 + r) * DIM + d0 + 4 * c4);
                xsh[4 * c4 + 0][r] = v.x; xsh[4 * c4 + 1][r] = v.y;
                xsh[4 * c4 + 2][r] = v.z; xsh[4 * c4 + 3][r] = v.w;
            }
            for (int f = tid; f < BK * BD / 4; f += 256) {
                int r = f >> 3, c4 = f & 7;
                float4 v = *(const float4*)(emb + (size_t)(kt + r) * DIM + d0 + 4 * c4);
                esh[4 * c4 + 0][r] = v.x; esh[4 * c4 + 1][r] = v.y;
                esh[4 * c4 + 2][r] = v.z; esh[4 * c4 + 3][r] = v.w;
            }
            __syncthreads();
            for (int dd = 0; dd < BD; ++dd) {
                float4 xv  = *(const float4*)&xsh[dd][4 * trow];
                float4 ev0 = *(const float4*)&esh[dd][8 * tcol];
                float4 ev1 = *(const float4*)&esh[dd][8 * tcol + 4];
                float xr[4] = { xv.x, xv.y, xv.z, xv.w };
                float ec[8] = { ev0.x, ev0.y, ev0.z, ev0.w, ev1.x, ev1.y, ev1.z, ev1.w };
                for (int r = 0; r < 4; ++r)
                    for (int c = 0; c < 8; ++c)
                        acc[r][c] = fmaf(xr[r], ec[c], acc[r][c]);
            }
            __syncthreads();
        }
        for (int c = 0; c < 8; ++c) {
            int   code = kt + 8 * tcol + c;
            float se   = emb_sq[code];
            for (int r = 0; r < 4; ++r) {
                float a  = sx[r] + se;
                float dv = a - 2.0f * acc[r][c];
                if (dv < bd[r]) { bd[r] = dv; bi[r] = code; }
            }
        }
    }
    for (int off = 1; off < 16; off <<= 1) {
        for (int r = 0; r < 4; ++r) {
            float od = __shfl_xor(bd[r], off);
            int   oi = __shfl_xor(bi[r], off);
            if (od < bd[r] || (od == bd[r] && oi < bi[r])) { bd[r] = od; bi[r] = oi; }
        }
    }
    if (tcol == 0)
        for (int r = 0; r < 4; ++r)
            enc[row0 + 4 * trow + r] = bi[r];
}

__global__ void out_kernel(const float* __restrict__ lat,
                           const float* __restrict__ emb,
                           const int* __restrict__ gold,
                           const int* __restrict__ enc,
                           float* __restrict__ out,
                           int* __restrict__ counter) {
#pragma clang fp contract(off)
    const int gid  = blockIdx.x * blockDim.x + threadIdx.x;
    const int row  = gid >> 6;
    const int lane = threadIdx.x & 63;
    if (row >= N_ROWS) return;
    const int idx = enc[row];
    const float4* e4 = (const float4*)(emb + (size_t)idx * DIM);
    float4*       q4 = (float4*)(out + (size_t)row * DIM);
    q4[lane]      = e4[lane];
    q4[lane + 64] = e4[lane + 64];
    float r = 0.0f;
    if (lane < 32) {
        const int b = lane >> 3, j = lane & 7;
        const float* ep = emb + (size_t)idx * DIM + b * 128 + j;
        const float* xp = lat + (size_t)row * DIM + b * 128 + j;
        for (int i = 0; i < 16; ++i) {
            float dq = ep[8 * i] - xp[8 * i];
            float s  = dq * dq;
            r = (i == 0) ? s : (r + s);
        }
    }
    for (int m = 1; m <= 16; m <<= 1) {
        float o = __shfl_xor(r, m);
        r = r + o;
    }
    if (lane == 0) {
        float mean = r * (1.0f / 512.0f);
        float v    = mean + 0.25f * mean;
        out[(size_t)N_ROWS * DIM + row]          = v;
        out[(size_t)N_ROWS * DIM + N_ROWS + row] = (float)idx;
        if (gold[row] == idx) atomicAdd(counter, 1);
    }
}

// ---------------------------------------------------------------------------
extern "C" void kernel_launch(void* const* d_in, const int* in_sizes, int n_in,
                              void* d_out, int out_size, void* d_ws, size_t ws_size,
                              hipStream_t stream) {
    (void)in_sizes; (void)n_in; (void)out_size;
    const int*   gold = (const int*)d_in[0];
    const float* lat  = (const float*)d_in[1];
    const float* emb  = (const float*)d_in[3];
    float* out = (float*)d_out;

    const size_t SZ_LATQ = (size_t)N_ROWS * DIM;         // 16 MB
    const size_t SZ_EMBQ = (size_t)KCB * DIM;            //  4 MB
    const size_t SZ_PK   = (size_t)N_ROWS * 512 * 4;     // 64 MB
    const size_t SZ_SMALL = (size_t)N_ROWS * 4 + (size_t)KCB * 4 + 256;
    const size_t NEEDED = SZ_LATQ + SZ_EMBQ + SZ_PK + SZ_SMALL;

    if (ws_size >= NEEDED) {
        unsigned char* w8 = (unsigned char*)d_ws;
        unsigned char* latq    = w8;
        unsigned char* embq    = w8 + SZ_LATQ;
        unsigned int*  packed  = (unsigned int*)(w8 + SZ_LATQ + SZ_EMBQ);
        float*         row_sq  = (float*)(w8 + SZ_LATQ + SZ_EMBQ + SZ_PK);
        float*         emb_sq  = row_sq + N_ROWS;
        int*           counter = (int*)(emb_sq + KCB);

        const int pre_blocks = SQ_BLOCKS + (N_ROWS + KCB) * (DIM / 8) / 256;
        pre_kernel<<<pre_blocks, 256, 0, stream>>>(
            lat, emb, row_sq, emb_sq, latq, embq, counter);
        gemm_kernel<<<(N_ROWS / 128) * (KCB / 128), 256, 0, stream>>>(
            latq, embq, emb_sq, packed);
        argmin_out_kernel<<<N_ROWS / 4, 256, 0, stream>>>(
            lat, emb, row_sq, emb_sq, packed, gold, out, counter);
        tail_kernel<<<1, 64, 0, stream>>>(counter, out);
    } else {
        float* row_sq  = (float*)d_ws;
        float* emb_sq  = row_sq + N_ROWS;
        int*   enc     = (int*)(emb_sq + KCB);
        int*   counter = enc + N_ROWS;
        hipMemsetAsync(counter, 0, sizeof(int), stream);
        sq_kernel<<<(N_ROWS + KCB) / 8, 256, 0, stream>>>(lat, emb, row_sq, emb_sq);
        dist_kernel<<<N_ROWS / BM, 256, 0, stream>>>(lat, emb, row_sq, emb_sq, enc);
        out_kernel<<<N_ROWS / 4, 256, 0, stream>>>(lat, emb, gold, enc, out, counter);
        tail_kernel<<<1, 64, 0, stream>>>(counter, out);
    }
}

// Round 9
// 533.834 us; speedup vs baseline: 1.3626x; 1.3626x over previous
//
#include <hip/hip_runtime.h>
#include <math.h>

#define N_ROWS 32768
#define KCB    8192
#define DIM    512
#define BETA   0.25f
#define MARGIN 2e-3f
#define FLAG_SLACK 1e-4f
#define CAND_CAP 256

typedef __attribute__((ext_vector_type(4))) float  f32x4;
typedef __attribute__((ext_vector_type(4))) int    i32x4;
typedef __attribute__((ext_vector_type(8))) int    i32x8;

__device__ __forceinline__ unsigned short f2h(float x) {
    _Float16 h = (_Float16)x;
    return *(unsigned short*)&h;
}
__device__ __forceinline__ float h2f(unsigned short u) {
    _Float16 h = *(_Float16*)&u;
    return (float)h;
}

// ---------------------------------------------------------------------------
// Kernel 1 (fused pre-pass): emb sq (numpy-exact pairwise tree) + fp8 convert.
// R9: lat-row sq REMOVED — argmin_out computes sx from its staged LDS copy
// with the bit-identical tree. pre keeps only KCB/8 = 1024 sq blocks (emb)
// + the convert blocks.
// ---------------------------------------------------------------------------
#define SQ_BLOCKS (KCB / 8)
__global__ __launch_bounds__(256) void pre_kernel(
        const float* __restrict__ lat, const float* __restrict__ emb,
        float* __restrict__ emb_sq,
        unsigned char* __restrict__ latq, unsigned char* __restrict__ embq,
        int* __restrict__ counter) {
    if (blockIdx.x < SQ_BLOCKS) {
#pragma clang fp contract(off)
        if (blockIdx.x == 0 && threadIdx.x == 0) *counter = 0;
        const int w    = threadIdx.x >> 6;
        const int lane = threadIdx.x & 63;
        const int half = lane >> 5;
        const int L    = lane & 31;
        const int b    = L >> 3, j = L & 7;
        const int row  = blockIdx.x * 8 + w * 2 + half;   // emb row
        const float* q = emb + (size_t)row * DIM + 128 * b + j;
        float a0 = q[0];
        float r  = a0 * a0;
        for (int i = 1; i < 16; ++i) {
            float a = q[8 * i];
            float s = a * a;
            r = r + s;
        }
        r = r + __shfl_xor(r, 1);
        r = r + __shfl_xor(r, 2);
        r = r + __shfl_xor(r, 4);
        r = r + __shfl_xor(r, 8);
        r = r + __shfl_xor(r, 16);
        if (L == 0) emb_sq[row] = r;
    } else {
        const size_t NL8 = (size_t)N_ROWS * DIM / 8;
        const size_t NE8 = (size_t)KCB * DIM / 8;
        size_t g = (size_t)(blockIdx.x - SQ_BLOCKS) * 256 + threadIdx.x;
        const float* src; unsigned char* dst; size_t i; float sc;
        if (g < NL8)            { src = lat; dst = latq; i = g;       sc = 1.0f; }
        else if (g < NL8 + NE8) { src = emb; dst = embq; i = g - NL8; sc = 8192.0f; }
        else return;
        float4 v0 = ((const float4*)src)[2 * i];
        float4 v1 = ((const float4*)src)[2 * i + 1];
        int lo = __builtin_amdgcn_cvt_pk_fp8_f32(v0.x * sc, v0.y * sc, 0,  false);
        lo     = __builtin_amdgcn_cvt_pk_fp8_f32(v0.z * sc, v0.w * sc, lo, true);
        int hi = __builtin_amdgcn_cvt_pk_fp8_f32(v1.x * sc, v1.y * sc, 0,  false);
        hi     = __builtin_amdgcn_cvt_pk_fp8_f32(v1.z * sc, v1.w * sc, hi, true);
        ((int2*)dst)[i] = make_int2(lo, hi);
    }
}

// ---------------------------------------------------------------------------
// Kernel 2: MX-scaled fp8 MFMA GEMM (transposed: D[code][latrow]).
// VERIFIED R1 kernel, unchanged (230-233 us, FETCH 49 MB, WRITE 101 MB,
// VGPR 96, no spill). 128x128 tile, 4 waves (2x2), BK=128 row-major
// [128][128B] LDS with both-sides XOR swizzle; 2-phase double-buffered
// prefetch with counted vmcnt(8); XCD-chunked supertile swizzle.
// Restructure attempts (R3-R5 256-tile, R8 direct-B) all tripped the
// allocator into scratch spill (500-850 MB phantom WRITE_SIZE) — the R1
// structure is the banked local optimum for this kernel.
// ---------------------------------------------------------------------------
__device__ __forceinline__ void load16_to_lds(const void* g, void* l) {
    __builtin_amdgcn_global_load_lds(
        (const __attribute__((address_space(1))) unsigned int*)g,
        (__attribute__((address_space(3))) unsigned int*)l, 16, 0, 0);
}

__global__ __launch_bounds__(256, 2) void gemm_kernel(
        const unsigned char* __restrict__ latq,
        const unsigned char* __restrict__ embq,
        const float* __restrict__ emb_sq,
        unsigned int* __restrict__ packed) {
    __shared__ unsigned char Ac[2][128 * 128];   // codes, 2 x 16 KB, swizzled
    __shared__ unsigned char Br[2][128 * 128];   // rows,  2 x 16 KB, swizzled

    const int tid   = threadIdx.x;
    const int w     = tid >> 6;
    const int lane  = tid & 63;
    const int q     = lane >> 4;
    const int m16   = lane & 15;

    // XCD-chunked supertile swizzle (bijective: 16384 = 8 XCD * 2048).
    const int b   = blockIdx.x;
    const int l   = (b & 7) * 2048 + (b >> 3);
    const int st  = l >> 9;          // 0..31
    const int r2  = l & 511;
    const int rg  = st & 7;          // 8 row groups of 32 tiles
    const int cg  = st >> 3;         // 4 code groups of 16 tiles
    const int row0  = (rg * 32 + (r2 & 31)) * 128;
    const int code0 = (cg * 16 + (r2 >> 5)) * 128;

    const int wc    = 64 * (w >> 1);
    const int rbase = 64 * (w & 1);

    // Staging: 32 chunks of 1 KB (16 A + 16 B), 8 per wave. Chunk h covers
    // 8 rows x 128 B. Lane l writes LDS linear h*1024 + l*16 (row h*8+(l>>3),
    // slot l&7). Source slot pre-swizzled: (l&7)^(l>>3), so
    // LDS[row][s] = global[row][s ^ (row&7)] (16B slot units).
    int soff[8];
#pragma unroll
    for (int i = 0; i < 8; ++i) {
        int cid   = w * 8 + i;
        int h     = cid & 15;
        int base0 = (cid < 16) ? code0 : row0;
        soff[i] = (base0 + h * 8 + (lane >> 3)) * DIM
                + (((lane & 7) ^ (lane >> 3)) << 4);
    }

#define STAGE(bsel, k0)                                                     \
    do {                                                                    \
        _Pragma("unroll")                                                   \
        for (int i = 0; i < 8; ++i) {                                       \
            int cid = w * 8 + i;                                            \
            const unsigned char* g =                                        \
                ((cid < 16) ? embq : latq) + soff[i] + (k0);                \
            unsigned char* dst = ((cid < 16) ? &Ac[bsel][0] : &Br[bsel][0]) \
                               + (cid & 15) * 1024;                         \
            load16_to_lds(g, dst);                                          \
        }                                                                   \
    } while (0)

    f32x4 acc[4][4];
#pragma unroll
    for (int r = 0; r < 4; ++r)
#pragma unroll
        for (int c = 0; c < 4; ++c) acc[r][c] = (f32x4){0.f, 0.f, 0.f, 0.f};

    const int sw = (m16 & 7) << 4;   // per-lane row-XOR (row&7 == m16&7)

    STAGE(0, 0);                     // prologue: tile 0 in flight

#pragma unroll
    for (int t = 0; t < 4; ++t) {
        const int bsel = t & 1;
        if (t < 3) STAGE((t + 1) & 1, (t + 1) * 128);   // prefetch tile t+1
        __builtin_amdgcn_sched_barrier(0);
        if (t < 3) { asm volatile("s_waitcnt vmcnt(8)" ::: "memory"); }
        else       { asm volatile("s_waitcnt vmcnt(0)" ::: "memory"); }
        __builtin_amdgcn_s_barrier();        // tile t visible to all waves
        __builtin_amdgcn_sched_barrier(0);

        // A fragments: lane (m16,q) holds K bytes q*32..q*32+31 of code row.
        i32x8 af[4];
#pragma unroll
        for (int r = 0; r < 4; ++r) {
            int roff = (wc + 16 * r + m16) * 128;
            i32x4 lo = *(const i32x4*)&Ac[bsel][roff + ((q * 32) ^ sw)];
            i32x4 hi = *(const i32x4*)&Ac[bsel][roff + ((q * 32 + 16) ^ sw)];
            af[r] = (i32x8){lo[0], lo[1], lo[2], lo[3],
                            hi[0], hi[1], hi[2], hi[3]};
        }
#pragma unroll
        for (int c = 0; c < 4; ++c) {
            int roff = (rbase + 16 * c + m16) * 128;
            i32x4 lo = *(const i32x4*)&Br[bsel][roff + ((q * 32) ^ sw)];
            i32x4 hi = *(const i32x4*)&Br[bsel][roff + ((q * 32 + 16) ^ sw)];
            i32x8 bv = (i32x8){lo[0], lo[1], lo[2], lo[3],
                               hi[0], hi[1], hi[2], hi[3]};
#pragma unroll
            for (int r = 0; r < 4; ++r)
                acc[r][c] = __builtin_amdgcn_mfma_scale_f32_16x16x128_f8f6f4(
                    af[r], bv, acc[r][c],
                    0, 0,                 // cbsz=fp8(e4m3), blgp=fp8(e4m3)
                    0, 0x7F7F7F7F,        // scale A: e8m0 127 -> 1.0
                    0, 0x7F7F7F7F);       // scale B: e8m0 127 -> 1.0
        }
        __builtin_amdgcn_sched_barrier(0);
        __builtin_amdgcn_s_barrier();        // all waves done reading buf
        __builtin_amdgcn_sched_barrier(0);
    }
#undef STAGE

    float sev[4][4];
#pragma unroll
    for (int r = 0; r < 4; ++r)
#pragma unroll
        for (int reg = 0; reg < 4; ++reg)
            sev[r][reg] = emb_sq[code0 + wc + 16 * r + 4 * q + reg];

    // epilogue (sx-free): s_rel = se - 2^-12*dotq ; group min + nibble bitmap
    const float inv = 1.0f / 4096.0f;
#pragma unroll
    for (int c = 0; c < 4; ++c) {
        unsigned pk[4];
#pragma unroll
        for (int r = 0; r < 4; ++r) {
            float s0 = sev[r][0] - acc[r][c][0] * inv;
            float s1 = sev[r][1] - acc[r][c][1] * inv;
            float s2 = sev[r][2] - acc[r][c][2] * inv;
            float s3 = sev[r][3] - acc[r][c][3] * inv;
            float mn = fminf(fminf(s0, s1), fminf(s2, s3));
            mn = fminf(mn, __shfl_xor(mn, 16));
            mn = fminf(mn, __shfl_xor(mn, 32));
            float t = mn + MARGIN;
            unsigned nib = (s0 <= t ? 1u : 0u) | (s1 <= t ? 2u : 0u)
                         | (s2 <= t ? 4u : 0u) | (s3 <= t ? 8u : 0u);
            nib <<= (4 * q);
            nib |= (unsigned)__shfl_xor((int)nib, 16);
            nib |= (unsigned)__shfl_xor((int)nib, 32);
            pk[r] = ((unsigned)f2h(mn)) | (nib << 16);
        }
        if (lane < 16) {
            int grow = row0 + rbase + 16 * c + m16;
            int base = (code0 + wc) >> 4;
            *(uint4*)&packed[(size_t)grow * 512 + base] =
                make_uint4(pk[0], pk[1], pk[2], pk[3]);
        }
    }
}

// ---------------------------------------------------------------------------
// Kernel 3 (fused): global min of fp16 group mins -> flagged groups ->
// candidate codes -> exact fp32 rescore -> outputs.
// R9: sx (lat row sumsq) computed HERE from the staged LDS row with the
// bit-identical pairwise tree (same element order, contract(off), same
// shfl_xor dataflow as the old pre_kernel sq pass — lanes 0-31 replicate
// pre's half-wave; LDS floats are the same bits as global).
// ---------------------------------------------------------------------------
__global__ __launch_bounds__(256) void argmin_out_kernel(
        const float* __restrict__ lat, const float* __restrict__ emb,
        const float* __restrict__ emb_sq,
        const unsigned int* __restrict__ packed,
        const int* __restrict__ gold,
        float* __restrict__ out, int* __restrict__ counter) {
    __shared__ float xs[4][DIM];
    __shared__ int   s_cnt[4];
    __shared__ int   s_list[4][CAND_CAP];
    const int w    = threadIdx.x >> 6;
    const int lane = threadIdx.x & 63;
    const int row  = blockIdx.x * 4 + w;

    {
        const float4* xp = (const float4*)(lat + (size_t)row * DIM);
        ((float4*)xs[w])[lane]      = xp[lane];
        ((float4*)xs[w])[lane + 64] = xp[lane + 64];
    }
    const float* xw = xs[w];

    // sx from LDS — bit-identical to the old pre_kernel tree.
    float sx;
    {
#pragma clang fp contract(off)
        const int L = lane & 31;
        const int b = L >> 3, j = L & 7;
        const float* q = xw + 128 * b + j;
        float a0 = q[0];
        float r  = a0 * a0;
        for (int i = 1; i < 16; ++i) {
            float a = q[8 * i];
            float s = a * a;
            r = r + s;
        }
        r = r + __shfl_xor(r, 1);
        r = r + __shfl_xor(r, 2);
        r = r + __shfl_xor(r, 4);
        r = r + __shfl_xor(r, 8);
        r = r + __shfl_xor(r, 16);
        sx = r;
    }

    unsigned u[8];
    {
        const uint4* tb = (const uint4*)(packed + (size_t)row * 512 + lane * 8);
        uint4 v0 = tb[0], v1 = tb[1];
        u[0] = v0.x; u[1] = v0.y; u[2] = v0.z; u[3] = v0.w;
        u[4] = v1.x; u[5] = v1.y; u[6] = v1.z; u[7] = v1.w;
    }
    float tm[8];
#pragma unroll
    for (int j = 0; j < 8; ++j) tm[j] = h2f((unsigned short)(u[j] & 0xFFFFu));
    float m = tm[0];
#pragma unroll
    for (int j = 1; j < 8; ++j) m = fminf(m, tm[j]);
#pragma unroll
    for (int off = 1; off < 64; off <<= 1)
        m = fminf(m, __shfl_xor(m, off));
    const float thresh = m + (MARGIN + FLAG_SLACK);

    if (lane == 0) s_cnt[w] = 0;
    __syncthreads();
#pragma unroll
    for (int j = 0; j < 8; ++j) {
        if (tm[j] <= thresh) {
            int g = lane * 8 + j;
            unsigned bm = u[j] >> 16;
            while (bm) {
                int b = __ffs(bm) - 1;
                bm &= bm - 1;
                int pos = atomicAdd(&s_cnt[w], 1);
                if (pos < CAND_CAP) s_list[w][pos] = g * 16 + b;
            }
        }
    }
    __syncthreads();
    const int cnt = min(s_cnt[w], CAND_CAP);

    float bd = INFINITY;
    int   bi = 0x7fffffff;
    for (int base = 0; base < cnt; base += 64) {
        int ci = base + lane;
        float dvl = INFINITY;
        int   cl  = 0x7fffffff;
        if (ci < cnt) {
            int code = s_list[w][ci];
            const float* ep = emb + (size_t)code * DIM;
            float acc = 0.0f;
            for (int d = 0; d < DIM; d += 8) {
                float ev[8], xv[8];
#pragma unroll
                for (int t = 0; t < 8; ++t) { ev[t] = ep[d + t]; xv[t] = xw[d + t]; }
#pragma unroll
                for (int t = 0; t < 8; ++t) acc = fmaf(xv[t], ev[t], acc);
            }
            float a = sx + emb_sq[code];
            dvl = a - 2.0f * acc;
            cl  = code;
        }
        if (dvl < bd || (dvl == bd && cl < bi)) { bd = dvl; bi = cl; }
    }
#pragma unroll
    for (int off = 1; off < 64; off <<= 1) {
        float od = __shfl_xor(bd, off);
        int   oi = __shfl_xor(bi, off);
        if (od < bd || (od == bd && oi < bi)) { bd = od; bi = oi; }
    }
    const int idx = bi;

    const float4* e4 = (const float4*)(emb + (size_t)idx * DIM);
    float4*       q4 = (float4*)(out + (size_t)row * DIM);
    q4[lane]      = e4[lane];
    q4[lane + 64] = e4[lane + 64];

    float r = 0.0f;
    if (lane < 32) {
        const int b = lane >> 3, j = lane & 7;
        const float* ep = emb + (size_t)idx * DIM + b * 128 + j;
        const float* xp = xw + b * 128 + j;
        for (int i = 0; i < 16; ++i) {
            float dq = ep[8 * i] - xp[8 * i];
            float s  = dq * dq;
            r = (i == 0) ? s : (r + s);
        }
    }
    for (int mm = 1; mm <= 16; mm <<= 1) {
        float o = __shfl_xor(r, mm);
        r = r + o;
    }
    if (lane == 0) {
        float mean = r * (1.0f / 512.0f);
        float v    = mean + 0.25f * mean;
        out[(size_t)N_ROWS * DIM + row]          = v;
        out[(size_t)N_ROWS * DIM + N_ROWS + row] = (float)idx;
        if (gold[row] == idx) atomicAdd(counter, 1);
    }
}

__global__ void tail_kernel(const int* __restrict__ counter,
                            float* __restrict__ out) {
    if (threadIdx.x == 0 && blockIdx.x == 0) {
        const size_t off = (size_t)N_ROWS * DIM + 2 * (size_t)N_ROWS;
        out[off]     = (float)(*counter);
        out[off + 1] = (float)N_ROWS;
    }
}

// ---------------------------------------------------------------------------
// Fallback path (tiny ws): R1 fp32 dist + separate sq/out kernels.
// ---------------------------------------------------------------------------
__global__ __launch_bounds__(256) void sq_kernel(
        const float* __restrict__ lat, const float* __restrict__ emb,
        float* __restrict__ row_sq, float* __restrict__ emb_sq) {
#pragma clang fp contract(off)
    const int w    = threadIdx.x >> 6;
    const int lane = threadIdx.x & 63;
    const int half = lane >> 5;
    const int L    = lane & 31;
    const int b    = L >> 3, j = L & 7;
    const int row  = blockIdx.x * 8 + w * 2 + half;
    if (row >= N_ROWS + KCB) return;
    const float* p = (row < N_ROWS) ? (lat + (size_t)row * DIM)
                                    : (emb + (size_t)(row - N_ROWS) * DIM);
    const float* q = p + 128 * b + j;
    float a0 = q[0];
    float r  = a0 * a0;
    for (int i = 1; i < 16; ++i) {
        float a = q[8 * i];
        float s = a * a;
        r = r + s;
    }
    r = r + __shfl_xor(r, 1);
    r = r + __shfl_xor(r, 2);
    r = r + __shfl_xor(r, 4);
    r = r + __shfl_xor(r, 8);
    r = r + __shfl_xor(r, 16);
    if (L == 0) {
        if (row < N_ROWS) row_sq[row] = r;
        else              emb_sq[row - N_ROWS] = r;
    }
}

#define BM 64
#define BK 128
#define BD 32
__global__ __launch_bounds__(256) void dist_kernel(
        const float* __restrict__ lat, const float* __restrict__ emb,
        const float* __restrict__ row_sq, const float* __restrict__ emb_sq,
        int* __restrict__ enc) {
    __shared__ float xsh[BD][BM];
    __shared__ float esh[BD][BK];
    const int tid  = threadIdx.x;
    const int trow = tid >> 4;
    const int tcol = tid & 15;
    const int row0 = blockIdx.x * BM;
    float bd[4]; int bi[4];
    for (int i = 0; i < 4; ++i) { bd[i] = INFINITY; bi[i] = 0; }
    float sx[4];
    for (int i = 0; i < 4; ++i) sx[i] = row_sq[row0 + 4 * trow + i];
    for (int kt = 0; kt < KCB; kt += BK) {
        float acc[4][8] = {};
        for (int d0 = 0; d0 < DIM; d0 += BD) {
            for (int f = tid; f < BM * BD / 4; f += 256) {
                int r = f >> 3, c4 = f & 7;
                float4 v = *(const float4*)(lat + (size_t)(row0 + r) * DIM + d0 + 4 * c4);
                xsh[4 * c4 + 0][r] = v.x; xsh[4 * c4 + 1][r] = v.y;
                xsh[4 * c4 + 2][r] = v.z; xsh[4 * c4 + 3][r] = v.w;
            }
            for (int f = tid; f < BK * BD / 4; f += 256) {
                int r = f >> 3, c4 = f & 7;
                float4 v = *(const float4*)(emb + (size_t)(kt + r) * DIM + d0 + 4 * c4);
                esh[4 * c4 + 0][r] = v.x; esh[4 * c4 + 1][r] = v.y;
                esh[4 * c4 + 2][r] = v.z; esh[4 * c4 + 3][r] = v.w;
            }
            __syncthreads();
            for (int dd = 0; dd < BD; ++dd) {
                float4 xv  = *(const float4*)&xsh[dd][4 * trow];
                float4 ev0 = *(const float4*)&esh[dd][8 * tcol];
                float4 ev1 = *(const float4*)&esh[dd][8 * tcol + 4];
                float xr[4] = { xv.x, xv.y, xv.z, xv.w };
                float ec[8] = { ev0.x, ev0.y, ev0.z, ev0.w, ev1.x, ev1.y, ev1.z, ev1.w };
                for (int r = 0; r < 4; ++r)
                    for (int c = 0; c < 8; ++c)
                        acc[r][c] = fmaf(xr[r], ec[c], acc[r][c]);
            }
            __syncthreads();
        }
        for (int c = 0; c < 8; ++c) {
            int   code = kt + 8 * tcol + c;
            float se   = emb_sq[code];
            for (int r = 0; r < 4; ++r) {
                float a  = sx[r] + se;
                float dv = a - 2.0f * acc[r][c];
                if (dv < bd[r]) { bd[r] = dv; bi[r] = code; }
            }
        }
    }
    for (int off = 1; off < 16; off <<= 1) {
        for (int r = 0; r < 4; ++r) {
            float od = __shfl_xor(bd[r], off);
            int   oi = __shfl_xor(bi[r], off);
            if (od < bd[r] || (od == bd[r] && oi < bi[r])) { bd[r] = od; bi[r] = oi; }
        }
    }
    if (tcol == 0)
        for (int r = 0; r < 4; ++r)
            enc[row0 + 4 * trow + r] = bi[r];
}

__global__ void out_kernel(const float* __restrict__ lat,
                           const float* __restrict__ emb,
                           const int* __restrict__ gold,
                           const int* __restrict__ enc,
                           float* __restrict__ out,
                           int* __restrict__ counter) {
#pragma clang fp contract(off)
    const int gid  = blockIdx.x * blockDim.x + threadIdx.x;
    const int row  = gid >> 6;
    const int lane = threadIdx.x & 63;
    if (row >= N_ROWS) return;
    const int idx = enc[row];
    const float4* e4 = (const float4*)(emb + (size_t)idx * DIM);
    float4*       q4 = (float4*)(out + (size_t)row * DIM);
    q4[lane]      = e4[lane];
    q4[lane + 64] = e4[lane + 64];
    float r = 0.0f;
    if (lane < 32) {
        const int b = lane >> 3, j = lane & 7;
        const float* ep = emb + (size_t)idx * DIM + b * 128 + j;
        const float* xp = lat + (size_t)row * DIM + b * 128 + j;
        for (int i = 0; i < 16; ++i) {
            float dq = ep[8 * i] - xp[8 * i];
            float s  = dq * dq;
            r = (i == 0) ? s : (r + s);
        }
    }
    for (int m = 1; m <= 16; m <<= 1) {
        float o = __shfl_xor(r, m);
        r = r + o;
    }
    if (lane == 0) {
        float mean = r * (1.0f / 512.0f);
        float v    = mean + 0.25f * mean;
        out[(size_t)N_ROWS * DIM + row]          = v;
        out[(size_t)N_ROWS * DIM + N_ROWS + row] = (float)idx;
        if (gold[row] == idx) atomicAdd(counter, 1);
    }
}

// ---------------------------------------------------------------------------
extern "C" void kernel_launch(void* const* d_in, const int* in_sizes, int n_in,
                              void* d_out, int out_size, void* d_ws, size_t ws_size,
                              hipStream_t stream) {
    (void)in_sizes; (void)n_in; (void)out_size;
    const int*   gold = (const int*)d_in[0];
    const float* lat  = (const float*)d_in[1];
    const float* emb  = (const float*)d_in[3];
    float* out = (float*)d_out;

    const size_t SZ_LATQ = (size_t)N_ROWS * DIM;         // 16 MB
    const size_t SZ_EMBQ = (size_t)KCB * DIM;            //  4 MB
    const size_t SZ_PK   = (size_t)N_ROWS * 512 * 4;     // 64 MB
    const size_t SZ_SMALL = (size_t)N_ROWS * 4 + (size_t)KCB * 4 + 256;
    const size_t NEEDED = SZ_LATQ + SZ_EMBQ + SZ_PK + SZ_SMALL;

    if (ws_size >= NEEDED) {
        unsigned char* w8 = (unsigned char*)d_ws;
        unsigned char* latq    = w8;
        unsigned char* embq    = w8 + SZ_LATQ;
        unsigned int*  packed  = (unsigned int*)(w8 + SZ_LATQ + SZ_EMBQ);
        float*         row_sq  = (float*)(w8 + SZ_LATQ + SZ_EMBQ + SZ_PK);
        float*         emb_sq  = row_sq + N_ROWS;
        int*           counter = (int*)(emb_sq + KCB);

        const int pre_blocks = SQ_BLOCKS + (N_ROWS + KCB) * (DIM / 8) / 256;
        pre_kernel<<<pre_blocks, 256, 0, stream>>>(
            lat, emb, emb_sq, latq, embq, counter);
        gemm_kernel<<<(N_ROWS / 128) * (KCB / 128), 256, 0, stream>>>(
            latq, embq, emb_sq, packed);
        argmin_out_kernel<<<N_ROWS / 4, 256, 0, stream>>>(
            lat, emb, emb_sq, packed, gold, out, counter);
        tail_kernel<<<1, 64, 0, stream>>>(counter, out);
    } else {
        float* row_sq  = (float*)d_ws;
        float* emb_sq  = row_sq + N_ROWS;
        int*   enc     = (int*)(emb_sq + KCB);
        int*   counter = enc + N_ROWS;
        hipMemsetAsync(counter, 0, sizeof(int), stream);
        sq_kernel<<<(N_ROWS + KCB) / 8, 256, 0, stream>>>(lat, emb, row_sq, emb_sq);
        dist_kernel<<<N_ROWS / BM, 256, 0, stream>>>(lat, emb, row_sq, emb_sq, enc);
        out_kernel<<<N_ROWS / 4, 256, 0, stream>>>(lat, emb, gold, enc, out, counter);
        tail_kernel<<<1, 64, 0, stream>>>(counter, out);
    }
}